// Round 12
// baseline (649.982 us; speedup 1.0000x reference)
//
#include <hip/hip_runtime.h>

typedef __attribute__((ext_vector_type(8))) short bf16x8;
typedef __attribute__((ext_vector_type(4))) float f32x4;
typedef __attribute__((ext_vector_type(2))) float f32x2;

static __device__ __forceinline__ unsigned short f2bf(float f) {
    unsigned int u = __float_as_uint(f);
    u += 0x7fffu + ((u >> 16) & 1u);   // round-to-nearest-even
    return (unsigned short)(u >> 16);
}
static __device__ __forceinline__ float bf2f(unsigned short h) {
    return __uint_as_float(((unsigned int)h) << 16);
}

#define BSH 6
#define BUCKET 64
#define NBMAX 1600
#define CHSH 13

// ---------------- structs ----------------

struct Rel {
    const int* src; const int* dst; int E; int nb; int Ndst;
    int hblk0, hnblk;
    int sblk0, snblk;
    int oblk0;
    int shift;                 // ssrc stores (s << shift) byte offsets
    int* bcnt; int* boff; int* bcur;
    unsigned* pairs; unsigned* ssrc; int* goff; float* invd;
};
struct Rels { Rel r[3]; };

struct PrepArgs {
    const float* W[10];
    const float* Wa[10];
    const float* b1a; const float* b1b; const float* b2a; const float* b2b;
};

// ---------------- prep + bucket-hist (merged) ----------------

__global__ void prep_hist_k(PrepArgs pa, unsigned short* __restrict__ Wt,
                            float* __restrict__ bc1, float* __restrict__ bc2,
                            Rels R, int prepBlocks) {
    int bid = blockIdx.x;
    if (bid < prepBlocks) {
        if (bid < 640) {
            int slot = bid >> 6;
            int i = ((bid & 63) << 8) + threadIdx.x;
            float v = pa.W[slot][i];
            const float* w2 = pa.Wa[slot];
            if (w2) v += w2[i];
            int k = i >> 7, n = i & 127;
            Wt[slot * 16384 + n * 128 + k] = f2bf(v);
        } else {
            int t = threadIdx.x;
            if (t < 128) bc1[t] = pa.b1a[t] + pa.b1b[t];
            else bc2[t - 128] = pa.b2a[t - 128] + pa.b2b[t - 128];
        }
        return;
    }
    int hb = bid - prepBlocks;
    const Rel* r;
    if (hb < R.r[1].hblk0) r = &R.r[0];
    else if (hb < R.r[2].hblk0) r = &R.r[1];
    else r = &R.r[2];
    __shared__ int h[NBMAX];
    for (int i = threadIdx.x; i < r->nb; i += 256) h[i] = 0;
    __syncthreads();
    for (int e = (hb - r->hblk0) * 256 + threadIdx.x; e < r->E; e += r->hnblk * 256)
        atomicAdd(&h[r->dst[e] >> BSH], 1);
    __syncthreads();
    for (int i = threadIdx.x; i < r->nb; i += 256)
        if (h[i]) atomicAdd(&r->bcnt[i], h[i]);
}

// ---------------- scan + scatter ----------------

__global__ void bscan3_k(Rels R) {
    const Rel* r = &R.r[blockIdx.x];
    __shared__ int s[1024];
    int t = threadIdx.x;
    int nb = r->nb;
    int e0 = 2 * t, e1 = 2 * t + 1;
    int v0 = (e0 < nb) ? r->bcnt[e0] : 0;
    int v1 = (e1 < nb) ? r->bcnt[e1] : 0;
    s[t] = v0 + v1;
    __syncthreads();
    for (int o = 1; o < 1024; o <<= 1) {
        int x = (t >= o) ? s[t - o] : 0;
        __syncthreads();
        s[t] += x;
        __syncthreads();
    }
    int P = s[t] - (v0 + v1);
    if (e0 <= nb) { r->boff[e0] = P; if (e0 < nb) r->bcur[e0] = 0; }
    if (e1 <= nb) { r->boff[e1] = P + v0; if (e1 < nb) r->bcur[e1] = 0; }
}

__global__ __launch_bounds__(256) void bscatter3_k(Rels R) {
    const Rel* r;
    int bid = blockIdx.x;
    if (bid < R.r[1].sblk0) r = &R.r[0];
    else if (bid < R.r[2].sblk0) r = &R.r[1];
    else r = &R.r[2];
    __shared__ int h[NBMAX];
    __shared__ int base[NBMAX];
    int t = threadIdx.x;
    int nb = r->nb, E = r->E;
    for (int i = t; i < nb; i += 256) h[i] = 0;
    __syncthreads();
    int e0 = (bid - r->sblk0) * 8192;
    for (int i = 0; i < 32; i++) {
        int e = e0 + i * 256 + t;
        if (e < E) atomicAdd(&h[r->dst[e] >> BSH], 1);
    }
    __syncthreads();
    for (int i = t; i < nb; i += 256) {
        int c = h[i];
        base[i] = c ? (r->boff[i] + atomicAdd(&r->bcur[i], c)) : 0;
    }
    __syncthreads();
    for (int i = t; i < nb; i += 256) h[i] = 0;
    __syncthreads();
    for (int i = 0; i < 32; i++) {
        int e = e0 + i * 256 + t;
        if (e < E) {
            int d = r->dst[e];
            int b = d >> BSH;
            int pos = base[b] + atomicAdd(&h[b], 1);
            r->pairs[pos] = ((unsigned)(d & (BUCKET - 1)) << 17) | (unsigned)r->src[e];
        }
    }
}

// ---------------- per-bucket counting sort (device body) ----------------
// bin = ((d&7)<<7) | ((d>>3)<<4) | ch; run (16 bins) = (wave w=d&7, row r=d>>3).
static __device__ void sortb_body(const Rels& R, int bid) {
    const Rel* r;
    if (bid < R.r[1].oblk0) r = &R.r[0];
    else if (bid < R.r[2].oblk0) r = &R.r[1];
    else r = &R.r[2];
    int b = bid - r->oblk0;
    __shared__ int cnt[1024];
    __shared__ int sc[256];
    int t = threadIdx.x;
    for (int i = t; i < 1024; i += 256) cnt[i] = 0;
    __syncthreads();
    int j0 = r->boff[b], j1 = r->boff[b + 1];
    for (int j = j0 + t; j < j1; j += 256) {
        unsigned p = r->pairs[j];
        int d = (p >> 17) & 63;
        int ch = (int)((p & 0x1ffffu) >> CHSH); if (ch > 15) ch = 15;
        int bin = ((d & 7) << 7) | ((d >> 3) << 4) | ch;
        atomicAdd(&cnt[bin], 1);
    }
    __syncthreads();
    if (t < 64) {
        int b0 = ((t & 7) << 7) | ((t >> 3) << 4);
        int c = 0;
#pragma unroll
        for (int i = 0; i < 16; i++) c += cnt[b0 + i];
        int dd = (b << BSH) + t;
        if (dd < r->Ndst) r->invd[dd] = 1.f / (float)(c > 0 ? c : 1);
    }
    int c0 = cnt[4 * t], c1 = cnt[4 * t + 1], c2 = cnt[4 * t + 2], c3 = cnt[4 * t + 3];
    int tot = c0 + c1 + c2 + c3;
    sc[t] = tot;
    __syncthreads();
    for (int o = 1; o < 256; o <<= 1) {
        int x = (t >= o) ? sc[t - o] : 0;
        __syncthreads();
        sc[t] += x;
        __syncthreads();
    }
    int base = j0 + sc[t] - tot;
    if ((t & 3) == 0) r->goff[b * 64 + (t >> 2)] = base;
    cnt[4 * t] = base;
    cnt[4 * t + 1] = base + c0;
    cnt[4 * t + 2] = base + c0 + c1;
    cnt[4 * t + 3] = base + c0 + c1 + c2;
    if (t == 0 && b == r->nb - 1) r->goff[r->nb * 64] = r->E;
    __syncthreads();
    int shift = r->shift;
    for (int j = j0 + t; j < j1; j += 256) {
        unsigned p = r->pairs[j];
        int d = (p >> 17) & 63;
        int ch = (int)((p & 0x1ffffu) >> CHSH); if (ch > 15) ch = 15;
        int bin = ((d & 7) << 7) | ((d >> 3) << 4) | ch;
        int pos = atomicAdd(&cnt[bin], 1);
        r->ssrc[pos] = (p & 0x1ffffu) << shift;
    }
}

// ---------------- MFMA GEMM body ----------------

struct GemmJobs {
    const void* Akw; int Nkw;
    const unsigned short* Wk1; const float* bk; unsigned short* Zkw;
    const unsigned short* Wk2; unsigned char* Ckw8;
    const void* Art; int Nrt;
    const unsigned short* Wr1; const float* br; unsigned short* Zrt;
    const unsigned short* Wr2; unsigned short* Crt2;
    const unsigned short* Wr3; unsigned short* Crt3;
    int kwBlocks;
};

template <int AF32>
static __device__ void gemm_body(const GemmJobs& G, int bid) {
    bool iskw = bid < G.kwBlocks;
    const void* A = iskw ? G.Akw : G.Art;
    int N = iskw ? G.Nkw : G.Nrt;
    int lane = threadIdx.x & 63;
    int r16 = lane & 15, g = lane >> 4;
    int row0 = (iskw ? bid : bid - G.kwBlocks) * 64 + (threadIdx.x >> 6) * 16;
    int arow = row0 + r16;
    int arow_c = arow < N ? arow : N - 1;

    bf16x8 af[4];
    if (AF32) {
        const float* Af = (const float*)A + (size_t)arow_c * 128 + g * 8;
#pragma unroll
        for (int kc = 0; kc < 4; kc++) {
            float4 u0 = *(const float4*)(Af + kc * 32);
            float4 u1 = *(const float4*)(Af + kc * 32 + 4);
            bf16x8 rr;
            rr[0] = (short)f2bf(u0.x); rr[1] = (short)f2bf(u0.y);
            rr[2] = (short)f2bf(u0.z); rr[3] = (short)f2bf(u0.w);
            rr[4] = (short)f2bf(u1.x); rr[5] = (short)f2bf(u1.y);
            rr[6] = (short)f2bf(u1.z); rr[7] = (short)f2bf(u1.w);
            af[kc] = rr;
        }
    } else {
        const bf16x8* Ar = (const bf16x8*)((const unsigned short*)A + (size_t)arow_c * 128);
#pragma unroll
        for (int kc = 0; kc < 4; kc++) af[kc] = Ar[kc * 4 + g];
    }

    if (iskw) {
        f32x4 acc1[8], acc2[8];
#pragma unroll
        for (int ct = 0; ct < 8; ct++) { f32x4 z = {0.f,0.f,0.f,0.f}; acc1[ct] = z; acc2[ct] = z; }
#pragma unroll
        for (int kc = 0; kc < 4; kc++) {
#pragma unroll
            for (int ct = 0; ct < 8; ct++) {
                int wo = ((ct * 16 + r16) << 7) + kc * 32 + g * 8;
                bf16x8 b1 = *(const bf16x8*)(G.Wk1 + wo);
                acc1[ct] = __builtin_amdgcn_mfma_f32_16x16x32_bf16(af[kc], b1, acc1[ct], 0, 0, 0);
                bf16x8 b2 = *(const bf16x8*)(G.Wk2 + wo);
                acc2[ct] = __builtin_amdgcn_mfma_f32_16x16x32_bf16(af[kc], b2, acc2[ct], 0, 0, 0);
            }
        }
#pragma unroll
        for (int ct = 0; ct < 8; ct++) {
            int col = ct * 16 + r16;
            float bb = G.bk[col];
#pragma unroll
            for (int j = 0; j < 4; j++) {
                int r = row0 + g * 4 + j;
                if (r < N) {
                    G.Zkw[(size_t)r * 128 + col] = f2bf(acc1[ct][j] + bb);
                    float v2 = acc2[ct][j];
                    int pk = __builtin_amdgcn_cvt_pk_fp8_f32(v2, v2, 0, false);
                    G.Ckw8[(size_t)r * 128 + col] = (unsigned char)(pk & 0xff);
                }
            }
        }
    } else {
        f32x4 acc1[8], acc2[8], acc3[8];
#pragma unroll
        for (int ct = 0; ct < 8; ct++) {
            f32x4 z = {0.f,0.f,0.f,0.f}; acc1[ct] = z; acc2[ct] = z; acc3[ct] = z;
        }
#pragma unroll
        for (int kc = 0; kc < 4; kc++) {
#pragma unroll
            for (int ct = 0; ct < 8; ct++) {
                int wo = ((ct * 16 + r16) << 7) + kc * 32 + g * 8;
                bf16x8 b1 = *(const bf16x8*)(G.Wr1 + wo);
                acc1[ct] = __builtin_amdgcn_mfma_f32_16x16x32_bf16(af[kc], b1, acc1[ct], 0, 0, 0);
                bf16x8 b2 = *(const bf16x8*)(G.Wr2 + wo);
                acc2[ct] = __builtin_amdgcn_mfma_f32_16x16x32_bf16(af[kc], b2, acc2[ct], 0, 0, 0);
                bf16x8 b3 = *(const bf16x8*)(G.Wr3 + wo);
                acc3[ct] = __builtin_amdgcn_mfma_f32_16x16x32_bf16(af[kc], b3, acc3[ct], 0, 0, 0);
            }
        }
#pragma unroll
        for (int ct = 0; ct < 8; ct++) {
            int col = ct * 16 + r16;
            float bb = G.br[col];
#pragma unroll
            for (int j = 0; j < 4; j++) {
                int r = row0 + g * 4 + j;
                if (r < N) {
                    G.Zrt[(size_t)r * 128 + col] = f2bf(acc1[ct][j] + bb);
                    G.Crt2[(size_t)r * 128 + col] = f2bf(acc2[ct][j]);
                    G.Crt3[(size_t)r * 128 + col] = f2bf(acc3[ct][j]);
                }
            }
        }
    }
}

__global__ __launch_bounds__(256) void gemm_sort_k(GemmJobs G, Rels R, int gemmBlocks) {
    if ((int)blockIdx.x < gemmBlocks) gemm_body<1>(G, blockIdx.x);
    else sortb_body(R, blockIdx.x - gemmBlocks);
}

__global__ __launch_bounds__(256) void gemm_l2_k(GemmJobs G) {
    gemm_body<0>(G, blockIdx.x);
}

// ---------------- bucket aggregation (dual-stream row walk) ----------------
// R8 structure: one 64-dst bucket/block, 8 waves, LDS accumulator, half-wave
// (h) edge split, scalar (uniform) offset loads. NEW: each row iteration walks
// TWO independent edge streams (kw: rel-a + rel-b of the same row; rt: rows r
// and r+4) so 16 loads are in flight and row boundaries never drain to zero.
// kw flush combines both rels -> one LDS flush per row.

template <int F>   // 0: bf16 (uint2/lane), 1: fp8 (uint/lane)
static __device__ __forceinline__ void acc_batch(const uint2* v, const unsigned* wv,
                                                 f32x2& a01, f32x2& a23) {
#pragma unroll
    for (int k = 0; k < 8; k++) {
        if (F == 0) {
            f32x2 x01 = { __uint_as_float(v[k].x << 16), __uint_as_float(v[k].x & 0xffff0000u) };
            f32x2 x23 = { __uint_as_float(v[k].y << 16), __uint_as_float(v[k].y & 0xffff0000u) };
            a01 += x01; a23 += x23;
        } else {
            auto lo = __builtin_amdgcn_cvt_pk_f32_fp8(wv[k], false);
            auto hi = __builtin_amdgcn_cvt_pk_f32_fp8(wv[k], true);
            a01[0] += lo[0]; a01[1] += lo[1];
            a23[0] += hi[0]; a23[1] += hi[1];
        }
    }
}

template <int F>
static __device__ __forceinline__ void tail_accum(const unsigned* __restrict__ spw,
                                                  int j, int len,
                                                  const char* __restrict__ Y, int lb, int h,
                                                  f32x2& a01, f32x2& a23) {
    if (j >= len) return;
#pragma unroll
    for (int k = 0; k < 8; k++) {
        int e = j + 2 * k + h;
        int ec = e < len ? e : len - 1;
        bool live = e < len;
        unsigned o = spw[ec];
        if (F == 0) {
            uint2 v = *(const uint2*)(Y + o + lb);
            unsigned vx = live ? v.x : 0u, vy = live ? v.y : 0u;
            f32x2 x01 = { __uint_as_float(vx << 16), __uint_as_float(vx & 0xffff0000u) };
            f32x2 x23 = { __uint_as_float(vy << 16), __uint_as_float(vy & 0xffff0000u) };
            a01 += x01; a23 += x23;
        } else {
            unsigned vv = *(const unsigned*)(Y + o + lb);
            vv = live ? vv : 0u;
            auto lo = __builtin_amdgcn_cvt_pk_f32_fp8(vv, false);
            auto hi = __builtin_amdgcn_cvt_pk_f32_fp8(vv, true);
            a01[0] += lo[0]; a01[1] += lo[1];
            a23[0] += hi[0]; a23[1] += hi[1];
        }
    }
}

template <int F0, int F1>
static __device__ __forceinline__ void dual_accum(
    const unsigned* __restrict__ sp0, int len0, const char* __restrict__ Y0, int lb0,
    const unsigned* __restrict__ sp1, int len1, const char* __restrict__ Y1, int lb1,
    int h, f32x2& p01, f32x2& p23, f32x2& q01, f32x2& q23) {
    int nf0 = len0 & ~15, nf1 = len1 & ~15;
    int j0 = 0, j1 = 0;
    while (j0 < nf0 || j1 < nf1) {       // lens are wave-uniform -> scalar branches
        bool g0 = j0 < nf0, g1 = j1 < nf1;
        uint2 v0[8]; unsigned w0[8];
        uint2 v1[8]; unsigned w1[8];
        if (g0) {
#pragma unroll
            for (int k = 0; k < 8; k++) {
                unsigned oe = sp0[j0 + 2 * k];       // uniform -> s_load
                unsigned oo = sp0[j0 + 2 * k + 1];
                unsigned o = h ? oo : oe;
                if (F0 == 0) v0[k] = *(const uint2*)(Y0 + o + lb0);
                else w0[k] = *(const unsigned*)(Y0 + o + lb0);
            }
        }
        if (g1) {
#pragma unroll
            for (int k = 0; k < 8; k++) {
                unsigned oe = sp1[j1 + 2 * k];
                unsigned oo = sp1[j1 + 2 * k + 1];
                unsigned o = h ? oo : oe;
                if (F1 == 0) v1[k] = *(const uint2*)(Y1 + o + lb1);
                else w1[k] = *(const unsigned*)(Y1 + o + lb1);
            }
        }
        if (g0) { acc_batch<F0>(v0, w0, p01, p23); j0 += 16; }
        if (g1) { acc_batch<F1>(v1, w1, q01, q23); j1 += 16; }
    }
    tail_accum<F0>(sp0, nf0, len0, Y0, lb0, h, p01, p23);
    tail_accum<F1>(sp1, nf1, len1, Y1, lb1, h, q01, q23);
}

struct AggJob {
    const unsigned short* Zin; int Ndst;
    const unsigned* sp0; const int* goff0; const float* invd0; const void* Y0; int fmt0;
    const unsigned* sp1; const int* goff1; const float* invd1; const void* Y1; int fmt1;
    int nrel;
    float* OutF; unsigned short* OutB;
};

template <int RELU, int OUTBF16>
__global__ __launch_bounds__(512) void bagg2_k(AggJob JK, AggJob JR, int kwBlocks) {
    __shared__ float acc[BUCKET * 128];
    bool iskw = blockIdx.x < (unsigned)kwBlocks;
    AggJob J = iskw ? JK : JR;
    int b = iskw ? blockIdx.x : blockIdx.x - kwBlocks;
    int t = threadIdx.x;
    int dst0 = b << BSH;
    int nrow = J.Ndst - dst0; if (nrow > BUCKET) nrow = BUCKET;

    // init from Zin bf16 (swizzled: feature 4m+e at r*128 + e*32 + m)
    for (int c = t; c < BUCKET * 32; c += 512) {
        int r = c >> 5, m = c & 31;
        float z0 = 0.f, z1 = 0.f, z2 = 0.f, z3 = 0.f;
        if (r < nrow) {
            ushort4 z = *(const ushort4*)(J.Zin + (size_t)(dst0 + r) * 128 + (m << 2));
            z0 = bf2f(z.x); z1 = bf2f(z.y); z2 = bf2f(z.z); z3 = bf2f(z.w);
        }
        acc[r * 128 + m] = z0;
        acc[r * 128 + 32 + m] = z1;
        acc[r * 128 + 64 + m] = z2;
        acc[r * 128 + 96 + m] = z3;
    }
    __syncthreads();

    int w = t >> 6, lane = t & 63;
    int h = lane >> 5, q = lane & 31;
    int lb0 = J.fmt0 ? (q << 2) : (q << 3);
    int lb1 = J.fmt1 ? (q << 2) : (q << 3);

    if (J.nrel == 2) {
        // kw: rel-a (bf16) + rel-b (fp8) of the SAME row walked together
#pragma unroll 1
        for (int r = 0; r < 8; r++) {
            int gi = b * 64 + w * 8 + r;
            int a0 = __builtin_amdgcn_readfirstlane(J.goff0[gi]);
            int a1 = __builtin_amdgcn_readfirstlane(J.goff0[gi + 1]);
            int c0 = __builtin_amdgcn_readfirstlane(J.goff1[gi]);
            int c1 = __builtin_amdgcn_readfirstlane(J.goff1[gi + 1]);
            int lenA = a1 - a0, lenB = c1 - c0;
            if (lenA <= 0 && lenB <= 0) continue;
            int d = (r << 3) | w;
            f32x2 p01 = {0.f,0.f}, p23 = {0.f,0.f}, q01 = {0.f,0.f}, q23 = {0.f,0.f};
            dual_accum<0, 1>(J.sp0 + a0, lenA, (const char*)J.Y0, lb0,
                             J.sp1 + c0, lenB, (const char*)J.Y1, lb1,
                             h, p01, p23, q01, q23);
            float invA = J.invd0[dst0 + d];
            float invB = J.invd1[dst0 + d];
            float s0 = p01[0] * invA + q01[0] * invB;
            float s1 = p01[1] * invA + q01[1] * invB;
            float s2 = p23[0] * invA + q23[0] * invB;
            float s3 = p23[1] * invA + q23[1] * invB;
            s0 += __shfl_xor(s0, 32);
            s1 += __shfl_xor(s1, 32);
            s2 += __shfl_xor(s2, 32);
            s3 += __shfl_xor(s3, 32);
            int ba = d * 128 + q + h * 64;
            acc[ba] += h ? s2 : s0;
            acc[ba + 32] += h ? s3 : s1;
        }
    } else {
        // rt: rows r and r+4 of rel-c walked together
#pragma unroll 1
        for (int rp = 0; rp < 4; rp++) {
            int gi0 = b * 64 + w * 8 + rp;
            int gi1 = gi0 + 4;
            int a0 = __builtin_amdgcn_readfirstlane(J.goff0[gi0]);
            int a1 = __builtin_amdgcn_readfirstlane(J.goff0[gi0 + 1]);
            int c0 = __builtin_amdgcn_readfirstlane(J.goff0[gi1]);
            int c1 = __builtin_amdgcn_readfirstlane(J.goff0[gi1 + 1]);
            int len0 = a1 - a0, len1 = c1 - c0;
            if (len0 <= 0 && len1 <= 0) continue;
            int d0 = (rp << 3) | w, d1 = ((rp + 4) << 3) | w;
            f32x2 p01 = {0.f,0.f}, p23 = {0.f,0.f}, q01 = {0.f,0.f}, q23 = {0.f,0.f};
            dual_accum<0, 0>(J.sp0 + a0, len0, (const char*)J.Y0, lb0,
                             J.sp0 + c0, len1, (const char*)J.Y0, lb0,
                             h, p01, p23, q01, q23);
            if (len0 > 0) {
                float inv = J.invd0[dst0 + d0];
                float s0 = p01[0] * inv, s1 = p01[1] * inv;
                float s2 = p23[0] * inv, s3 = p23[1] * inv;
                s0 += __shfl_xor(s0, 32);
                s1 += __shfl_xor(s1, 32);
                s2 += __shfl_xor(s2, 32);
                s3 += __shfl_xor(s3, 32);
                int ba = d0 * 128 + q + h * 64;
                acc[ba] += h ? s2 : s0;
                acc[ba + 32] += h ? s3 : s1;
            }
            if (len1 > 0) {
                float inv = J.invd0[dst0 + d1];
                float s0 = q01[0] * inv, s1 = q01[1] * inv;
                float s2 = q23[0] * inv, s3 = q23[1] * inv;
                s0 += __shfl_xor(s0, 32);
                s1 += __shfl_xor(s1, 32);
                s2 += __shfl_xor(s2, 32);
                s3 += __shfl_xor(s3, 32);
                int ba = d1 * 128 + q + h * 64;
                acc[ba] += h ? s2 : s0;
                acc[ba + 32] += h ? s3 : s1;
            }
        }
    }
    __syncthreads();
    for (int c = t; c < BUCKET * 32; c += 512) {
        int r = c >> 5, m = c & 31;
        if (r < nrow) {
            float x0 = acc[r * 128 + m];
            float x1 = acc[r * 128 + 32 + m];
            float x2 = acc[r * 128 + 64 + m];
            float x3 = acc[r * 128 + 96 + m];
            if (RELU) {
                x0 = fmaxf(x0, 0.f); x1 = fmaxf(x1, 0.f);
                x2 = fmaxf(x2, 0.f); x3 = fmaxf(x3, 0.f);
            }
            size_t o = (size_t)(dst0 + r) * 128 + (m << 2);
            if (OUTBF16) {
                ushort4 ov;
                ov.x = f2bf(x0); ov.y = f2bf(x1); ov.z = f2bf(x2); ov.w = f2bf(x3);
                *(ushort4*)(J.OutB + o) = ov;
            } else {
                *(float4*)(J.OutF + o) = make_float4(x0, x1, x2, x3);
            }
        }
    }
}

// ---------------- launch ----------------

static inline size_t align256(size_t x) { return (x + 255) & ~size_t(255); }

extern "C" void kernel_launch(void* const* d_in, const int* in_sizes, int n_in,
                              void* d_out, int out_size, void* d_ws, size_t ws_size,
                              hipStream_t stream) {
    const float* x_kw = (const float*)d_in[0];
    const float* x_rt = (const float*)d_in[1];
    const int* src_a = (const int*)d_in[2];
    const int* dst_a = (const int*)d_in[3];
    const int* src_b = (const int*)d_in[4];
    const int* dst_b = (const int*)d_in[5];
    const int* src_c = (const int*)d_in[6];
    const int* dst_c = (const int*)d_in[7];
    const float *Wl1a = (const float*)d_in[8],  *bl1a = (const float*)d_in[9],  *Wr1a = (const float*)d_in[10];
    const float *Wl1b = (const float*)d_in[11], *bl1b = (const float*)d_in[12], *Wr1b = (const float*)d_in[13];
    const float *Wl1c = (const float*)d_in[14], *bl1c = (const float*)d_in[15], *Wr1c = (const float*)d_in[16];
    const float *Wl2a = (const float*)d_in[17], *bl2a = (const float*)d_in[18], *Wr2a = (const float*)d_in[19];
    const float *Wl2b = (const float*)d_in[20], *bl2b = (const float*)d_in[21], *Wr2b = (const float*)d_in[22];
    const float *Wl2c = (const float*)d_in[23], *bl2c = (const float*)d_in[24], *Wr2c = (const float*)d_in[25];

    const int NKW = in_sizes[0] / 128;
    const int NRT = in_sizes[1] / 128;
    const int EA = in_sizes[2], EB = in_sizes[4], EC = in_sizes[6];
    const int nb_kw = (NKW + BUCKET - 1) / BUCKET;
    const int nb_rt = (NRT + BUCKET - 1) / BUCKET;

    char* ws = (char*)d_ws;
    size_t off = 0;
    auto alloc = [&](size_t bytes) -> char* {
        off = align256(off);
        char* p = ws + off;
        off += bytes;
        return p;
    };
    unsigned short* Wt = (unsigned short*)alloc(10 * 16384 * 2);
    float* bc1 = (float*)alloc(128 * 4);
    float* bc2 = (float*)alloc(128 * 4);
    int* bcnt3 = (int*)alloc(3 * NBMAX * 4);
    int* bcur3 = (int*)alloc(3 * NBMAX * 4);
    int* boff_a = (int*)alloc((NBMAX + 1) * 4);
    int* boff_b = (int*)alloc((NBMAX + 1) * 4);
    int* boff_c = (int*)alloc((NBMAX + 1) * 4);
    int* goff_a = (int*)alloc(((size_t)nb_kw * 64 + 1) * 4);
    int* goff_b = (int*)alloc(((size_t)nb_kw * 64 + 1) * 4);
    int* goff_c = (int*)alloc(((size_t)nb_rt * 64 + 1) * 4);
    float* invd_a = (float*)alloc((size_t)NKW * 4);
    float* invd_b = (float*)alloc((size_t)NKW * 4);
    float* invd_c = (float*)alloc((size_t)NRT * 4);
    unsigned* pairs_a = (unsigned*)alloc((size_t)EA * 4);
    unsigned* pairs_b = (unsigned*)alloc((size_t)EB * 4);
    unsigned* pairs_c = (unsigned*)alloc((size_t)EC * 4);
    unsigned* sp_a = (unsigned*)alloc((size_t)EA * 4);
    unsigned* sp_b = (unsigned*)alloc((size_t)EB * 4);
    unsigned* sp_c = (unsigned*)alloc((size_t)EC * 4);
    unsigned short* Ya = (unsigned short*)alloc((size_t)NRT * 128 * 2);
    unsigned char*  Yb = (unsigned char*)alloc((size_t)NKW * 128);      // fp8
    unsigned short* Yc = (unsigned short*)alloc((size_t)NRT * 128 * 2);
    unsigned short* Zkw = (unsigned short*)alloc((size_t)NKW * 128 * 2);
    unsigned short* Zrt = (unsigned short*)alloc((size_t)NRT * 128 * 2);
    unsigned short* kw1_bf = (unsigned short*)alloc((size_t)NKW * 128 * 2);
    unsigned short* rt1_bf = (unsigned short*)alloc((size_t)NRT * 128 * 2);
    (void)ws_size;

    float* out_kw = (float*)d_out;
    float* out_rt = out_kw + (size_t)NKW * 128;

    // ---- Rels ----
    Rels R;
    int hA = 128, hB = 128, hC = 64;
    int sA = (EA + 8191) / 8192, sB = (EB + 8191) / 8192, sC = (EC + 8191) / 8192;
    R.r[0] = {src_a, dst_a, EA, nb_kw, NKW, 0, hA, 0, sA, 0, 8,
              bcnt3, boff_a, bcur3, pairs_a, sp_a, goff_a, invd_a};
    R.r[1] = {src_b, dst_b, EB, nb_kw, NKW, hA, hB, sA, sB, nb_kw, 7,   // fp8 rows: 128 B
              bcnt3 + NBMAX, boff_b, bcur3 + NBMAX, pairs_b, sp_b, goff_b, invd_b};
    R.r[2] = {src_c, dst_c, EC, nb_rt, NRT, hA + hB, hC, sA + sB, sC, 2 * nb_kw, 8,
              bcnt3 + 2 * NBMAX, boff_c, bcur3 + 2 * NBMAX, pairs_c, sp_c, goff_c, invd_c};

    // ---- prep + hist ----
    hipMemsetAsync(bcnt3, 0, 3 * NBMAX * 4, stream);
    PrepArgs pa;
    pa.W[0] = Wr1a; pa.Wa[0] = Wr1b;
    pa.W[1] = Wl1a; pa.Wa[1] = nullptr;
    pa.W[2] = Wl1b; pa.Wa[2] = nullptr;
    pa.W[3] = Wl1c; pa.Wa[3] = nullptr;
    pa.W[4] = Wr1c; pa.Wa[4] = nullptr;
    pa.W[5] = Wr2a; pa.Wa[5] = Wr2b;
    pa.W[6] = Wl2a; pa.Wa[6] = nullptr;
    pa.W[7] = Wl2b; pa.Wa[7] = nullptr;
    pa.W[8] = Wl2c; pa.Wa[8] = nullptr;
    pa.W[9] = Wr2c; pa.Wa[9] = nullptr;
    pa.b1a = bl1a; pa.b1b = bl1b; pa.b2a = bl2a; pa.b2b = bl2b;
    prep_hist_k<<<641 + hA + hB + hC, 256, 0, stream>>>(pa, Wt, bc1, bc2, R, 641);
    unsigned short* W0 = Wt + 0 * 16384;
    unsigned short* W1 = Wt + 1 * 16384;
    unsigned short* W2 = Wt + 2 * 16384;
    unsigned short* W3 = Wt + 3 * 16384;
    unsigned short* W4 = Wt + 4 * 16384;
    unsigned short* W5 = Wt + 5 * 16384;
    unsigned short* W6 = Wt + 6 * 16384;
    unsigned short* W7 = Wt + 7 * 16384;
    unsigned short* W8 = Wt + 8 * 16384;
    unsigned short* W9 = Wt + 9 * 16384;

    bscan3_k<<<3, 1024, 0, stream>>>(R);
    bscatter3_k<<<sA + sB + sC, 256, 0, stream>>>(R);

    const int kwB = (NKW + 63) / 64, rtB = (NRT + 63) / 64;
    const int nsort = 2 * nb_kw + nb_rt;

    // ---- layer 1: gemms + bucket sort in one launch (independent) ----
    GemmJobs G1;
    G1.Akw = x_kw; G1.Nkw = NKW; G1.Wk1 = W0; G1.bk = bc1; G1.Zkw = Zkw; G1.Wk2 = W2; G1.Ckw8 = Yb;
    G1.Art = x_rt; G1.Nrt = NRT; G1.Wr1 = W4; G1.br = bl1c; G1.Zrt = Zrt;
    G1.Wr2 = W1; G1.Crt2 = Ya; G1.Wr3 = W3; G1.Crt3 = Yc;
    G1.kwBlocks = kwB;
    gemm_sort_k<<<kwB + rtB + nsort, 256, 0, stream>>>(G1, R, kwB + rtB);

    AggJob JK1 = {Zkw, NKW, sp_a, goff_a, invd_a, Ya, 0, sp_b, goff_b, invd_b, Yb, 1, 2,
                  nullptr, kw1_bf};
    AggJob JR1 = {Zrt, NRT, sp_c, goff_c, invd_c, Yc, 0, nullptr, nullptr, nullptr, nullptr, 0, 1,
                  nullptr, rt1_bf};
    bagg2_k<1, 1><<<nb_kw + nb_rt, 512, 0, stream>>>(JK1, JR1, nb_kw);

    // ---- layer 2 ----
    GemmJobs G2;
    G2.Akw = kw1_bf; G2.Nkw = NKW; G2.Wk1 = W5; G2.bk = bc2; G2.Zkw = Zkw; G2.Wk2 = W7; G2.Ckw8 = Yb;
    G2.Art = rt1_bf; G2.Nrt = NRT; G2.Wr1 = W9; G2.br = bl2c; G2.Zrt = Zrt;
    G2.Wr2 = W6; G2.Crt2 = Ya; G2.Wr3 = W8; G2.Crt3 = Yc;
    G2.kwBlocks = kwB;
    gemm_l2_k<<<kwB + rtB, 256, 0, stream>>>(G2);

    AggJob JK2 = {Zkw, NKW, sp_a, goff_a, invd_a, Ya, 0, sp_b, goff_b, invd_b, Yb, 1, 2,
                  out_kw, nullptr};
    AggJob JR2 = {Zrt, NRT, sp_c, goff_c, invd_c, Yc, 0, nullptr, nullptr, nullptr, nullptr, 0, 1,
                  out_rt, nullptr};
    bagg2_k<0, 0><<<nb_kw + nb_rt, 512, 0, stream>>>(JK2, JR2, nb_kw);
}

// Round 13
// 554.891 us; speedup vs baseline: 1.1714x; 1.1714x over previous
//
#include <hip/hip_runtime.h>

typedef __attribute__((ext_vector_type(8))) short bf16x8;
typedef __attribute__((ext_vector_type(4))) float f32x4;
typedef __attribute__((ext_vector_type(2))) float f32x2;

static __device__ __forceinline__ unsigned short f2bf(float f) {
    unsigned int u = __float_as_uint(f);
    u += 0x7fffu + ((u >> 16) & 1u);   // round-to-nearest-even
    return (unsigned short)(u >> 16);
}
static __device__ __forceinline__ float bf2f(unsigned short h) {
    return __uint_as_float(((unsigned int)h) << 16);
}

#define BSH 6
#define BUCKET 64
#define NBMAX 1600
#define CHSH 13
#define ASTRIDE 130   // padded LDS row stride (floats): conflict-free epilogue A-reads

// ---------------- prep ----------------

struct PrepArgs {
    const float* W[10];
    const float* Wa[10];
    const float* b1a; const float* b1b; const float* b2a; const float* b2b;
};

__global__ void prep_k(PrepArgs pa, unsigned short* __restrict__ Wt,
                       float* __restrict__ bc1, float* __restrict__ bc2) {
    int blk = blockIdx.x;
    if (blk < 640) {
        int slot = blk >> 6;
        int i = ((blk & 63) << 8) + threadIdx.x;
        float v = pa.W[slot][i];
        const float* w2 = pa.Wa[slot];
        if (w2) v += w2[i];
        int k = i >> 7, n = i & 127;
        Wt[slot * 16384 + n * 128 + k] = f2bf(v);
    } else {
        int t = threadIdx.x;
        if (t < 128) bc1[t] = pa.b1a[t] + pa.b1b[t];
        else bc2[t - 128] = pa.b2a[t - 128] + pa.b2b[t - 128];
    }
}

// ---------------- fused bucket build ----------------

struct Rel {
    const int* src; const int* dst; int E; int nb; int Ndst;
    int hblk0, hnblk;
    int sblk0, snblk;
    int oblk0;
    int* bcnt; int* boff; int* bcur;
    unsigned* pairs; unsigned* ssrc; int* goff; float* invd;
};
struct Rels { Rel r[3]; };

__global__ void bhist3_k(Rels R) {
    const Rel* r;
    int bid = blockIdx.x;
    if (bid < R.r[1].hblk0) r = &R.r[0];
    else if (bid < R.r[2].hblk0) r = &R.r[1];
    else r = &R.r[2];
    __shared__ int h[NBMAX];
    for (int i = threadIdx.x; i < r->nb; i += 256) h[i] = 0;
    __syncthreads();
    for (int e = (bid - r->hblk0) * 256 + threadIdx.x; e < r->E; e += r->hnblk * 256)
        atomicAdd(&h[r->dst[e] >> BSH], 1);
    __syncthreads();
    for (int i = threadIdx.x; i < r->nb; i += 256)
        if (h[i]) atomicAdd(&r->bcnt[i], h[i]);
}

__global__ void bscan3_k(Rels R) {
    const Rel* r = &R.r[blockIdx.x];
    __shared__ int s[1024];
    int t = threadIdx.x;
    int nb = r->nb;
    int e0 = 2 * t, e1 = 2 * t + 1;
    int v0 = (e0 < nb) ? r->bcnt[e0] : 0;
    int v1 = (e1 < nb) ? r->bcnt[e1] : 0;
    s[t] = v0 + v1;
    __syncthreads();
    for (int o = 1; o < 1024; o <<= 1) {
        int x = (t >= o) ? s[t - o] : 0;
        __syncthreads();
        s[t] += x;
        __syncthreads();
    }
    int P = s[t] - (v0 + v1);
    if (e0 <= nb) { r->boff[e0] = P; if (e0 < nb) r->bcur[e0] = 0; }
    if (e1 <= nb) { r->boff[e1] = P + v0; if (e1 < nb) r->bcur[e1] = 0; }
}

__global__ __launch_bounds__(256) void bscatter3_k(Rels R) {
    const Rel* r;
    int bid = blockIdx.x;
    if (bid < R.r[1].sblk0) r = &R.r[0];
    else if (bid < R.r[2].sblk0) r = &R.r[1];
    else r = &R.r[2];
    __shared__ int h[NBMAX];
    __shared__ int base[NBMAX];
    int t = threadIdx.x;
    int nb = r->nb, E = r->E;
    for (int i = t; i < nb; i += 256) h[i] = 0;
    __syncthreads();
    int e0 = (bid - r->sblk0) * 8192;
    for (int i = 0; i < 32; i++) {
        int e = e0 + i * 256 + t;
        if (e < E) atomicAdd(&h[r->dst[e] >> BSH], 1);
    }
    __syncthreads();
    for (int i = t; i < nb; i += 256) {
        int c = h[i];
        base[i] = c ? (r->boff[i] + atomicAdd(&r->bcur[i], c)) : 0;
    }
    __syncthreads();
    for (int i = t; i < nb; i += 256) h[i] = 0;
    __syncthreads();
    for (int i = 0; i < 32; i++) {
        int e = e0 + i * 256 + t;
        if (e < E) {
            int d = r->dst[e];
            int b = d >> BSH;
            int pos = base[b] + atomicAdd(&h[b], 1);
            r->pairs[pos] = ((unsigned)(d & (BUCKET - 1)) << 17) | (unsigned)r->src[e];
        }
    }
}

// bin = ((d&7)<<7) | ((d>>3)<<4) | ch; run (16 bins) = (wave w=d&7, row r=d>>3).
__global__ __launch_bounds__(256) void sortb3_k(Rels R) {
    const Rel* r;
    int bid = blockIdx.x;
    if (bid < R.r[1].oblk0) r = &R.r[0];
    else if (bid < R.r[2].oblk0) r = &R.r[1];
    else r = &R.r[2];
    int b = bid - r->oblk0;
    __shared__ int cnt[1024];
    __shared__ int sc[256];
    int t = threadIdx.x;
    for (int i = t; i < 1024; i += 256) cnt[i] = 0;
    __syncthreads();
    int j0 = r->boff[b], j1 = r->boff[b + 1];
    for (int j = j0 + t; j < j1; j += 256) {
        unsigned p = r->pairs[j];
        int d = (p >> 17) & 63;
        int ch = (int)((p & 0x1ffffu) >> CHSH); if (ch > 15) ch = 15;
        int bin = ((d & 7) << 7) | ((d >> 3) << 4) | ch;
        atomicAdd(&cnt[bin], 1);
    }
    __syncthreads();
    if (t < 64) {
        int b0 = ((t & 7) << 7) | ((t >> 3) << 4);
        int c = 0;
#pragma unroll
        for (int i = 0; i < 16; i++) c += cnt[b0 + i];
        int dd = (b << BSH) + t;
        if (dd < r->Ndst) r->invd[dd] = 1.f / (float)(c > 0 ? c : 1);
    }
    int c0 = cnt[4 * t], c1 = cnt[4 * t + 1], c2 = cnt[4 * t + 2], c3 = cnt[4 * t + 3];
    int tot = c0 + c1 + c2 + c3;
    sc[t] = tot;
    __syncthreads();
    for (int o = 1; o < 256; o <<= 1) {
        int x = (t >= o) ? sc[t - o] : 0;
        __syncthreads();
        sc[t] += x;
        __syncthreads();
    }
    int base = j0 + sc[t] - tot;
    if ((t & 3) == 0) r->goff[b * 64 + (t >> 2)] = base;
    cnt[4 * t] = base;
    cnt[4 * t + 1] = base + c0;
    cnt[4 * t + 2] = base + c0 + c1;
    cnt[4 * t + 3] = base + c0 + c1 + c2;
    if (t == 0 && b == r->nb - 1) r->goff[r->nb * 64] = r->E;
    __syncthreads();
    for (int j = j0 + t; j < j1; j += 256) {
        unsigned p = r->pairs[j];
        int d = (p >> 17) & 63;
        int ch = (int)((p & 0x1ffffu) >> CHSH); if (ch > 15) ch = 15;
        int bin = ((d & 7) << 7) | ((d >> 3) << 4) | ch;
        int pos = atomicAdd(&cnt[bin], 1);
        r->ssrc[pos] = p & 0x1ffffu;
    }
}

// ---------------- layer-1 MFMA GEMMs (one launch) ----------------
// kw blocks: Zkw = x_kw@W0+bc1 (bf16), Yb = x_kw@W2 (bf16)
// rt blocks: Zrt, Ya, Yc (bf16), shared A read. A is f32 (converted in-reg).

struct GemmJobs {
    const float* Akw; int Nkw;
    const unsigned short* Wk1; const float* bk; unsigned short* Zkw;
    const unsigned short* Wk2; unsigned short* Ckw;
    const float* Art; int Nrt;
    const unsigned short* Wr1; const float* br; unsigned short* Zrt;
    const unsigned short* Wr2; unsigned short* Crt2;
    const unsigned short* Wr3; unsigned short* Crt3;
    int kwBlocks;
};

__global__ __launch_bounds__(256) void gemm3_k(GemmJobs G) {
    int bid = blockIdx.x;
    bool iskw = bid < G.kwBlocks;
    const float* A = iskw ? G.Akw : G.Art;
    int N = iskw ? G.Nkw : G.Nrt;
    int lane = threadIdx.x & 63;
    int r16 = lane & 15, g = lane >> 4;
    int row0 = (iskw ? bid : bid - G.kwBlocks) * 64 + (threadIdx.x >> 6) * 16;
    int arow = row0 + r16;
    int arow_c = arow < N ? arow : N - 1;

    bf16x8 af[4];
    {
        const float* Af = A + (size_t)arow_c * 128 + g * 8;
#pragma unroll
        for (int kc = 0; kc < 4; kc++) {
            float4 u0 = *(const float4*)(Af + kc * 32);
            float4 u1 = *(const float4*)(Af + kc * 32 + 4);
            bf16x8 rr;
            rr[0] = (short)f2bf(u0.x); rr[1] = (short)f2bf(u0.y);
            rr[2] = (short)f2bf(u0.z); rr[3] = (short)f2bf(u0.w);
            rr[4] = (short)f2bf(u1.x); rr[5] = (short)f2bf(u1.y);
            rr[6] = (short)f2bf(u1.z); rr[7] = (short)f2bf(u1.w);
            af[kc] = rr;
        }
    }

    if (iskw) {
        f32x4 acc1[8], acc2[8];
#pragma unroll
        for (int ct = 0; ct < 8; ct++) { f32x4 z = {0.f,0.f,0.f,0.f}; acc1[ct] = z; acc2[ct] = z; }
#pragma unroll
        for (int kc = 0; kc < 4; kc++) {
#pragma unroll
            for (int ct = 0; ct < 8; ct++) {
                int wo = ((ct * 16 + r16) << 7) + kc * 32 + g * 8;
                bf16x8 b1 = *(const bf16x8*)(G.Wk1 + wo);
                acc1[ct] = __builtin_amdgcn_mfma_f32_16x16x32_bf16(af[kc], b1, acc1[ct], 0, 0, 0);
                bf16x8 b2 = *(const bf16x8*)(G.Wk2 + wo);
                acc2[ct] = __builtin_amdgcn_mfma_f32_16x16x32_bf16(af[kc], b2, acc2[ct], 0, 0, 0);
            }
        }
#pragma unroll
        for (int ct = 0; ct < 8; ct++) {
            int col = ct * 16 + r16;
            float bb = G.bk[col];
#pragma unroll
            for (int j = 0; j < 4; j++) {
                int r = row0 + g * 4 + j;
                if (r < N) {
                    G.Zkw[(size_t)r * 128 + col] = f2bf(acc1[ct][j] + bb);
                    G.Ckw[(size_t)r * 128 + col] = f2bf(acc2[ct][j]);
                }
            }
        }
    } else {
        f32x4 acc1[8], acc2[8], acc3[8];
#pragma unroll
        for (int ct = 0; ct < 8; ct++) {
            f32x4 z = {0.f,0.f,0.f,0.f}; acc1[ct] = z; acc2[ct] = z; acc3[ct] = z;
        }
#pragma unroll
        for (int kc = 0; kc < 4; kc++) {
#pragma unroll
            for (int ct = 0; ct < 8; ct++) {
                int wo = ((ct * 16 + r16) << 7) + kc * 32 + g * 8;
                bf16x8 b1 = *(const bf16x8*)(G.Wr1 + wo);
                acc1[ct] = __builtin_amdgcn_mfma_f32_16x16x32_bf16(af[kc], b1, acc1[ct], 0, 0, 0);
                bf16x8 b2 = *(const bf16x8*)(G.Wr2 + wo);
                acc2[ct] = __builtin_amdgcn_mfma_f32_16x16x32_bf16(af[kc], b2, acc2[ct], 0, 0, 0);
                bf16x8 b3 = *(const bf16x8*)(G.Wr3 + wo);
                acc3[ct] = __builtin_amdgcn_mfma_f32_16x16x32_bf16(af[kc], b3, acc3[ct], 0, 0, 0);
            }
        }
#pragma unroll
        for (int ct = 0; ct < 8; ct++) {
            int col = ct * 16 + r16;
            float bb = G.br[col];
#pragma unroll
            for (int j = 0; j < 4; j++) {
                int r = row0 + g * 4 + j;
                if (r < N) {
                    G.Zrt[(size_t)r * 128 + col] = f2bf(acc1[ct][j] + bb);
                    G.Crt2[(size_t)r * 128 + col] = f2bf(acc2[ct][j]);
                    G.Crt3[(size_t)r * 128 + col] = f2bf(acc3[ct][j]);
                }
            }
        }
    }
}

// ---------------- bucket aggregation (R7 structure) + optional fused L2 GEMM ----------------
// Block = one 64-dst bucket, 8 waves, LDS acc (stride 130). Wave w owns rows
// d=(r<<3)|w. Halves (h) process interleaved edges, 16 in flight, uint2 loads,
// packed f32x2 accumulate, shfl_xor(32) combine, non-atomic swizzled flush.
// GEPI=1: after relu-in-LDS, each wave runs the layer-2 GEMM for its 16-row
// A-tile straight from LDS (conflict-free b64 reads via the 130-stride pad).

struct AggJob {
    const unsigned short* Zin; int Ndst;
    const unsigned* sp0; const int* goff0; const float* invd0; const unsigned short* Y0;
    const unsigned* sp1; const int* goff1; const float* invd1; const unsigned short* Y1;
    int nrel;
    float* OutF; unsigned short* OutB;
    // fused layer-2 GEMM (GEPI=1): group0 waves -> Wg1(+bg1)->Cg1; group1 -> Wg2->Cg2 [,Wg3->Cg3]
    const unsigned short* Wg1; const float* bg1; unsigned short* Cg1;
    const unsigned short* Wg2; unsigned short* Cg2;
    const unsigned short* Wg3; unsigned short* Cg3;
};

template <int RELU, int OUTBF16, int GEPI>
__global__ __launch_bounds__(512, 8) void bagg2_k(AggJob JK, AggJob JR, int kwBlocks) {
    __shared__ float acc[BUCKET * ASTRIDE];
    bool iskw = blockIdx.x < (unsigned)kwBlocks;
    AggJob J = iskw ? JK : JR;
    int b = iskw ? blockIdx.x : blockIdx.x - kwBlocks;
    int t = threadIdx.x;
    int dst0 = b << BSH;
    int nrow = J.Ndst - dst0; if (nrow > BUCKET) nrow = BUCKET;

    // init from Zin bf16 (swizzled: feature 4m+e at r*ASTRIDE + e*32 + m); zero pad rows
    for (int c = t; c < BUCKET * 32; c += 512) {
        int r = c >> 5, m = c & 31;
        float z0 = 0.f, z1 = 0.f, z2 = 0.f, z3 = 0.f;
        if (r < nrow) {
            ushort4 z = *(const ushort4*)(J.Zin + (size_t)(dst0 + r) * 128 + (m << 2));
            z0 = bf2f(z.x); z1 = bf2f(z.y); z2 = bf2f(z.z); z3 = bf2f(z.w);
        }
        acc[r * ASTRIDE + m] = z0;
        acc[r * ASTRIDE + 32 + m] = z1;
        acc[r * ASTRIDE + 64 + m] = z2;
        acc[r * ASTRIDE + 96 + m] = z3;
    }
    __syncthreads();

    int w = t >> 6, lane = t & 63;
    int h = lane >> 5, q = lane & 31;
#pragma unroll 1
    for (int rel = 0; rel < J.nrel; rel++) {
        const unsigned* sp = rel ? J.sp1 : J.sp0;
        const int* goff = rel ? J.goff1 : J.goff0;
        const float* invd = rel ? J.invd1 : J.invd0;
        const unsigned short* Y = rel ? J.Y1 : J.Y0;
#pragma unroll 1
        for (int r = 0; r < 8; r++) {
            int g = b * 64 + w * 8 + r;
            int jg0 = goff[g], jg1 = goff[g + 1];
            if (jg0 >= jg1) continue;
            int d = (r << 3) | w;
            f32x2 a01 = {0.f, 0.f}, a23 = {0.f, 0.f};
#pragma unroll 1
            for (int j = jg0; j < jg1; j += 16) {
                uint2 v[8];
#pragma unroll
                for (int k = 0; k < 8; k++) {
                    int e = j + 2 * k + h;
                    e = e < jg1 ? e : jg1 - 1;
                    int s = (int)sp[e];
                    v[k] = *(const uint2*)(Y + ((size_t)s << 7) + (q << 2));
                }
#pragma unroll
                for (int k = 0; k < 8; k++) {
                    bool ok = (j + 2 * k + h) < jg1;
                    unsigned vx = ok ? v[k].x : 0u;
                    unsigned vy = ok ? v[k].y : 0u;
                    f32x2 x01 = { __uint_as_float(vx << 16),
                                  __uint_as_float(vx & 0xffff0000u) };
                    f32x2 x23 = { __uint_as_float(vy << 16),
                                  __uint_as_float(vy & 0xffff0000u) };
                    a01 += x01;
                    a23 += x23;
                }
            }
            a01[0] += __shfl_xor(a01[0], 32); a01[1] += __shfl_xor(a01[1], 32);
            a23[0] += __shfl_xor(a23[0], 32); a23[1] += __shfl_xor(a23[1], 32);
            float inv = invd[dst0 + d];
            float v0 = (h ? a23[0] : a01[0]) * inv;
            float v1 = (h ? a23[1] : a01[1]) * inv;
            int ba = d * ASTRIDE + q + h * 64;
            acc[ba] += v0;
            acc[ba + 32] += v1;
        }
    }
    __syncthreads();

    if (GEPI) {
        // relu in place (f32); A-tile stays in LDS, no global write of layer-1 act
        for (int c = t; c < BUCKET * 32; c += 512) {
            int r = c >> 5, m = c & 31;
            int ba = r * ASTRIDE + m;
            acc[ba] = fmaxf(acc[ba], 0.f);
            acc[ba + 32] = fmaxf(acc[ba + 32], 0.f);
            acc[ba + 64] = fmaxf(acc[ba + 64], 0.f);
            acc[ba + 96] = fmaxf(acc[ba + 96], 0.f);
        }
        __syncthreads();
        int r16 = lane & 15, gg = lane >> 4;
        int rg = (w & 3) * 16;
        // A-frags for rows rg+r16: feature f slot = (f&3)*32 + (f>>2)
        bf16x8 af[4];
        int rbase = (rg + r16) * ASTRIDE;
#pragma unroll
        for (int kc = 0; kc < 4; kc++) {
            int m2 = 2 * (kc * 4 + gg);
            float2 p0 = *(const float2*)&acc[rbase + m2];
            float2 p1 = *(const float2*)&acc[rbase + 32 + m2];
            float2 p2 = *(const float2*)&acc[rbase + 64 + m2];
            float2 p3 = *(const float2*)&acc[rbase + 96 + m2];
            bf16x8 rr;
            rr[0] = (short)f2bf(p0.x); rr[1] = (short)f2bf(p1.x);
            rr[2] = (short)f2bf(p2.x); rr[3] = (short)f2bf(p3.x);
            rr[4] = (short)f2bf(p0.y); rr[5] = (short)f2bf(p1.y);
            rr[6] = (short)f2bf(p2.y); rr[7] = (short)f2bf(p3.y);
            af[kc] = rr;
        }
        const unsigned short* WtA; unsigned short* CA; const float* biasA;
        const unsigned short* WtB = nullptr; unsigned short* CB = nullptr;
        if ((w >> 2) == 0) { WtA = J.Wg1; CA = J.Cg1; biasA = J.bg1; }
        else {
            WtA = J.Wg2; CA = J.Cg2; biasA = nullptr;
            if (J.Wg3) { WtB = J.Wg3; CB = J.Cg3; }
        }
        auto run_mat = [&](const unsigned short* Wt_, unsigned short* C_, const float* bias) {
#pragma unroll 1
            for (int ct = 0; ct < 8; ct++) {
                f32x4 a4 = {0.f, 0.f, 0.f, 0.f};
#pragma unroll
                for (int kc = 0; kc < 4; kc++) {
                    bf16x8 bfrag = *(const bf16x8*)(Wt_ + ((ct * 16 + r16) << 7) + kc * 32 + gg * 8);
                    a4 = __builtin_amdgcn_mfma_f32_16x16x32_bf16(af[kc], bfrag, a4, 0, 0, 0);
                }
                int col = ct * 16 + r16;
                float bb = bias ? bias[col] : 0.f;
#pragma unroll
                for (int jj = 0; jj < 4; jj++) {
                    int rloc = rg + gg * 4 + jj;
                    if (rloc < nrow)
                        C_[(size_t)(dst0 + rloc) * 128 + col] = f2bf(a4[jj] + bb);
                }
            }
        };
        run_mat(WtA, CA, biasA);
        if (WtB) run_mat(WtB, CB, nullptr);
        return;
    }

    for (int c = t; c < BUCKET * 32; c += 512) {
        int r = c >> 5, m = c & 31;
        if (r < nrow) {
            float x0 = acc[r * ASTRIDE + m];
            float x1 = acc[r * ASTRIDE + 32 + m];
            float x2 = acc[r * ASTRIDE + 64 + m];
            float x3 = acc[r * ASTRIDE + 96 + m];
            if (RELU) {
                x0 = fmaxf(x0, 0.f); x1 = fmaxf(x1, 0.f);
                x2 = fmaxf(x2, 0.f); x3 = fmaxf(x3, 0.f);
            }
            size_t o = (size_t)(dst0 + r) * 128 + (m << 2);
            if (OUTBF16) {
                ushort4 ov;
                ov.x = f2bf(x0); ov.y = f2bf(x1); ov.z = f2bf(x2); ov.w = f2bf(x3);
                *(ushort4*)(J.OutB + o) = ov;
            } else {
                *(float4*)(J.OutF + o) = make_float4(x0, x1, x2, x3);
            }
        }
    }
}

// ---------------- launch ----------------

static inline size_t align256(size_t x) { return (x + 255) & ~size_t(255); }

extern "C" void kernel_launch(void* const* d_in, const int* in_sizes, int n_in,
                              void* d_out, int out_size, void* d_ws, size_t ws_size,
                              hipStream_t stream) {
    const float* x_kw = (const float*)d_in[0];
    const float* x_rt = (const float*)d_in[1];
    const int* src_a = (const int*)d_in[2];
    const int* dst_a = (const int*)d_in[3];
    const int* src_b = (const int*)d_in[4];
    const int* dst_b = (const int*)d_in[5];
    const int* src_c = (const int*)d_in[6];
    const int* dst_c = (const int*)d_in[7];
    const float *Wl1a = (const float*)d_in[8],  *bl1a = (const float*)d_in[9],  *Wr1a = (const float*)d_in[10];
    const float *Wl1b = (const float*)d_in[11], *bl1b = (const float*)d_in[12], *Wr1b = (const float*)d_in[13];
    const float *Wl1c = (const float*)d_in[14], *bl1c = (const float*)d_in[15], *Wr1c = (const float*)d_in[16];
    const float *Wl2a = (const float*)d_in[17], *bl2a = (const float*)d_in[18], *Wr2a = (const float*)d_in[19];
    const float *Wl2b = (const float*)d_in[20], *bl2b = (const float*)d_in[21], *Wr2b = (const float*)d_in[22];
    const float *Wl2c = (const float*)d_in[23], *bl2c = (const float*)d_in[24], *Wr2c = (const float*)d_in[25];

    const int NKW = in_sizes[0] / 128;
    const int NRT = in_sizes[1] / 128;
    const int EA = in_sizes[2], EB = in_sizes[4], EC = in_sizes[6];
    const int nb_kw = (NKW + BUCKET - 1) / BUCKET;
    const int nb_rt = (NRT + BUCKET - 1) / BUCKET;

    char* ws = (char*)d_ws;
    size_t off = 0;
    auto alloc = [&](size_t bytes) -> char* {
        off = align256(off);
        char* p = ws + off;
        off += bytes;
        return p;
    };
    unsigned short* Wt = (unsigned short*)alloc(10 * 16384 * 2);
    float* bc1 = (float*)alloc(128 * 4);
    float* bc2 = (float*)alloc(128 * 4);
    int* bcnt3 = (int*)alloc(3 * NBMAX * 4);
    int* bcur3 = (int*)alloc(3 * NBMAX * 4);
    int* boff_a = (int*)alloc((NBMAX + 1) * 4);
    int* boff_b = (int*)alloc((NBMAX + 1) * 4);
    int* boff_c = (int*)alloc((NBMAX + 1) * 4);
    int* goff_a = (int*)alloc(((size_t)nb_kw * 64 + 1) * 4);
    int* goff_b = (int*)alloc(((size_t)nb_kw * 64 + 1) * 4);
    int* goff_c = (int*)alloc(((size_t)nb_rt * 64 + 1) * 4);
    float* invd_a = (float*)alloc((size_t)NKW * 4);
    float* invd_b = (float*)alloc((size_t)NKW * 4);
    float* invd_c = (float*)alloc((size_t)NRT * 4);
    unsigned* pairs_a = (unsigned*)alloc((size_t)EA * 4);
    unsigned* pairs_b = (unsigned*)alloc((size_t)EB * 4);
    unsigned* pairs_c = (unsigned*)alloc((size_t)EC * 4);
    unsigned* sp_a = (unsigned*)alloc((size_t)EA * 4);
    unsigned* sp_b = (unsigned*)alloc((size_t)EB * 4);
    unsigned* sp_c = (unsigned*)alloc((size_t)EC * 4);
    unsigned short* Ya = (unsigned short*)alloc((size_t)NRT * 128 * 2);
    unsigned short* Yb = (unsigned short*)alloc((size_t)NKW * 128 * 2);
    unsigned short* Yc = (unsigned short*)alloc((size_t)NRT * 128 * 2);
    unsigned short* Zkw = (unsigned short*)alloc((size_t)NKW * 128 * 2);
    unsigned short* Zrt = (unsigned short*)alloc((size_t)NRT * 128 * 2);
    unsigned short* Yb2 = (unsigned short*)alloc((size_t)NKW * 128 * 2);
    (void)ws_size;
    // layer-2 Y buffers for rt (5.12 MB each) alias dead pairs arrays (6.4 MB, dead after sortb3)
    unsigned short* Ya2 = (unsigned short*)pairs_a;
    unsigned short* Yc2 = (unsigned short*)pairs_b;

    float* out_kw = (float*)d_out;
    float* out_rt = out_kw + (size_t)NKW * 128;

    // ---- prep ----
    PrepArgs pa;
    pa.W[0] = Wr1a; pa.Wa[0] = Wr1b;
    pa.W[1] = Wl1a; pa.Wa[1] = nullptr;
    pa.W[2] = Wl1b; pa.Wa[2] = nullptr;
    pa.W[3] = Wl1c; pa.Wa[3] = nullptr;
    pa.W[4] = Wr1c; pa.Wa[4] = nullptr;
    pa.W[5] = Wr2a; pa.Wa[5] = Wr2b;
    pa.W[6] = Wl2a; pa.Wa[6] = nullptr;
    pa.W[7] = Wl2b; pa.Wa[7] = nullptr;
    pa.W[8] = Wl2c; pa.Wa[8] = nullptr;
    pa.W[9] = Wr2c; pa.Wa[9] = nullptr;
    pa.b1a = bl1a; pa.b1b = bl1b; pa.b2a = bl2a; pa.b2b = bl2b;
    prep_k<<<641, 256, 0, stream>>>(pa, Wt, bc1, bc2);
    unsigned short* W0 = Wt + 0 * 16384;
    unsigned short* W1 = Wt + 1 * 16384;
    unsigned short* W2 = Wt + 2 * 16384;
    unsigned short* W3 = Wt + 3 * 16384;
    unsigned short* W4 = Wt + 4 * 16384;
    unsigned short* W5 = Wt + 5 * 16384;
    unsigned short* W6 = Wt + 6 * 16384;
    unsigned short* W7 = Wt + 7 * 16384;
    unsigned short* W8 = Wt + 8 * 16384;
    unsigned short* W9 = Wt + 9 * 16384;

    // ---- fused bucket build ----
    hipMemsetAsync(bcnt3, 0, 3 * NBMAX * 4, stream);
    Rels R;
    int hA = 128, hB = 128, hC = 64;
    int sA = (EA + 8191) / 8192, sB = (EB + 8191) / 8192, sC = (EC + 8191) / 8192;
    R.r[0] = {src_a, dst_a, EA, nb_kw, NKW, 0, hA, 0, sA, 0,
              bcnt3, boff_a, bcur3, pairs_a, sp_a, goff_a, invd_a};
    R.r[1] = {src_b, dst_b, EB, nb_kw, NKW, hA, hB, sA, sB, nb_kw,
              bcnt3 + NBMAX, boff_b, bcur3 + NBMAX, pairs_b, sp_b, goff_b, invd_b};
    R.r[2] = {src_c, dst_c, EC, nb_rt, NRT, hA + hB, hC, sA + sB, sC, 2 * nb_kw,
              bcnt3 + 2 * NBMAX, boff_c, bcur3 + 2 * NBMAX, pairs_c, sp_c, goff_c, invd_c};
    bhist3_k<<<hA + hB + hC, 256, 0, stream>>>(R);
    bscan3_k<<<3, 1024, 0, stream>>>(R);
    bscatter3_k<<<sA + sB + sC, 256, 0, stream>>>(R);
    sortb3_k<<<2 * nb_kw + nb_rt, 256, 0, stream>>>(R);

    const int kwB = (NKW + 63) / 64, rtB = (NRT + 63) / 64;

    // ---- layer 1 GEMMs ----
    GemmJobs G1;
    G1.Akw = x_kw; G1.Nkw = NKW; G1.Wk1 = W0; G1.bk = bc1; G1.Zkw = Zkw; G1.Wk2 = W2; G1.Ckw = Yb;
    G1.Art = x_rt; G1.Nrt = NRT; G1.Wr1 = W4; G1.br = bl1c; G1.Zrt = Zrt;
    G1.Wr2 = W1; G1.Crt2 = Ya; G1.Wr3 = W3; G1.Crt3 = Yc;
    G1.kwBlocks = kwB;
    gemm3_k<<<kwB + rtB, 256, 0, stream>>>(G1);

    // ---- layer-1 agg + fused layer-2 GEMM ----
    AggJob JK1 = {Zkw, NKW, sp_a, goff_a, invd_a, Ya, sp_b, goff_b, invd_b, Yb, 2,
                  nullptr, nullptr,
                  W5, bc2, Zkw,      // Zkw2 = relu(kw1)@ (Wr2a+Wr2b) + bc2 (in place, own rows)
                  W7, Yb2,           // Yb2  = relu(kw1)@ Wl2b
                  nullptr, nullptr};
    AggJob JR1 = {Zrt, NRT, sp_c, goff_c, invd_c, Yc, nullptr, nullptr, nullptr, nullptr, 1,
                  nullptr, nullptr,
                  W9, bl2c, Zrt,     // Zrt2 = relu(rt1)@ Wr2c + bl2c
                  W6, Ya2,           // Ya2  = relu(rt1)@ Wl2a
                  W8, Yc2};          // Yc2  = relu(rt1)@ Wl2c
    bagg2_k<1, 1, 1><<<nb_kw + nb_rt, 512, 0, stream>>>(JK1, JR1, nb_kw);

    // ---- layer-2 agg ----
    AggJob JK2 = {Zkw, NKW, sp_a, goff_a, invd_a, Ya2, sp_b, goff_b, invd_b, Yb2, 2,
                  out_kw, nullptr,
                  nullptr, nullptr, nullptr, nullptr, nullptr, nullptr, nullptr};
    AggJob JR2 = {Zrt, NRT, sp_c, goff_c, invd_c, Yc2, nullptr, nullptr, nullptr, nullptr, 1,
                  out_rt, nullptr,
                  nullptr, nullptr, nullptr, nullptr, nullptr, nullptr, nullptr};
    bagg2_k<0, 0, 0><<<nb_kw + nb_rt, 512, 0, stream>>>(JK2, JR2, nb_kw);
}

// Round 14
// 550.453 us; speedup vs baseline: 1.1808x; 1.0081x over previous
//
#include <hip/hip_runtime.h>

typedef __attribute__((ext_vector_type(8))) short bf16x8;
typedef __attribute__((ext_vector_type(4))) float f32x4;
typedef __attribute__((ext_vector_type(2))) float f32x2;

static __device__ __forceinline__ unsigned short f2bf(float f) {
    unsigned int u = __float_as_uint(f);
    u += 0x7fffu + ((u >> 16) & 1u);   // round-to-nearest-even
    return (unsigned short)(u >> 16);
}
static __device__ __forceinline__ float bf2f(unsigned short h) {
    return __uint_as_float(((unsigned int)h) << 16);
}

#define BSH 6
#define BUCKET 64
#define NBMAX 1600
#define CHSH 13
#define ASTRIDE 130   // padded LDS row stride (floats): conflict-free epilogue A-reads

// ---------------- structs ----------------

struct Rel {
    const int* src; const int* dst; int E; int nb; int Ndst;
    int hblk0, hnblk;
    int sblk0, snblk;
    int oblk0;
    int* bcnt; int* boff; int* bcur;
    unsigned* pairs; unsigned* ssrc; int* goff; float* invd;
};
struct Rels { Rel r[3]; };

struct PrepArgs {
    const float* W[10];
    const float* Wa[10];
    const float* b1a; const float* b1b; const float* b2a; const float* b2b;
};

// ---------------- prep + bucket-hist (merged) ----------------

__global__ void prep_hist_k(PrepArgs pa, unsigned short* __restrict__ Wt,
                            float* __restrict__ bc1, float* __restrict__ bc2,
                            Rels R, int prepBlocks) {
    int bid = blockIdx.x;
    if (bid < prepBlocks) {
        if (bid < 640) {
            int slot = bid >> 6;
            int i = ((bid & 63) << 8) + threadIdx.x;
            float v = pa.W[slot][i];
            const float* w2 = pa.Wa[slot];
            if (w2) v += w2[i];
            int k = i >> 7, n = i & 127;
            Wt[slot * 16384 + n * 128 + k] = f2bf(v);
        } else {
            int t = threadIdx.x;
            if (t < 128) bc1[t] = pa.b1a[t] + pa.b1b[t];
            else bc2[t - 128] = pa.b2a[t - 128] + pa.b2b[t - 128];
        }
        return;
    }
    int hb = bid - prepBlocks;
    const Rel* r;
    if (hb < R.r[1].hblk0) r = &R.r[0];
    else if (hb < R.r[2].hblk0) r = &R.r[1];
    else r = &R.r[2];
    __shared__ int h[NBMAX];
    for (int i = threadIdx.x; i < r->nb; i += 256) h[i] = 0;
    __syncthreads();
    for (int e = (hb - r->hblk0) * 256 + threadIdx.x; e < r->E; e += r->hnblk * 256)
        atomicAdd(&h[r->dst[e] >> BSH], 1);
    __syncthreads();
    for (int i = threadIdx.x; i < r->nb; i += 256)
        if (h[i]) atomicAdd(&r->bcnt[i], h[i]);
}

// ---------------- scan + scatter ----------------

__global__ void bscan3_k(Rels R) {
    const Rel* r = &R.r[blockIdx.x];
    __shared__ int s[1024];
    int t = threadIdx.x;
    int nb = r->nb;
    int e0 = 2 * t, e1 = 2 * t + 1;
    int v0 = (e0 < nb) ? r->bcnt[e0] : 0;
    int v1 = (e1 < nb) ? r->bcnt[e1] : 0;
    s[t] = v0 + v1;
    __syncthreads();
    for (int o = 1; o < 1024; o <<= 1) {
        int x = (t >= o) ? s[t - o] : 0;
        __syncthreads();
        s[t] += x;
        __syncthreads();
    }
    int P = s[t] - (v0 + v1);
    if (e0 <= nb) { r->boff[e0] = P; if (e0 < nb) r->bcur[e0] = 0; }
    if (e1 <= nb) { r->boff[e1] = P + v0; if (e1 < nb) r->bcur[e1] = 0; }
}

__global__ __launch_bounds__(256) void bscatter3_k(Rels R) {
    const Rel* r;
    int bid = blockIdx.x;
    if (bid < R.r[1].sblk0) r = &R.r[0];
    else if (bid < R.r[2].sblk0) r = &R.r[1];
    else r = &R.r[2];
    __shared__ int h[NBMAX];
    __shared__ int base[NBMAX];
    int t = threadIdx.x;
    int nb = r->nb, E = r->E;
    for (int i = t; i < nb; i += 256) h[i] = 0;
    __syncthreads();
    int e0 = (bid - r->sblk0) * 8192;
    for (int i = 0; i < 32; i++) {
        int e = e0 + i * 256 + t;
        if (e < E) atomicAdd(&h[r->dst[e] >> BSH], 1);
    }
    __syncthreads();
    for (int i = t; i < nb; i += 256) {
        int c = h[i];
        base[i] = c ? (r->boff[i] + atomicAdd(&r->bcur[i], c)) : 0;
    }
    __syncthreads();
    for (int i = t; i < nb; i += 256) h[i] = 0;
    __syncthreads();
    for (int i = 0; i < 32; i++) {
        int e = e0 + i * 256 + t;
        if (e < E) {
            int d = r->dst[e];
            int b = d >> BSH;
            int pos = base[b] + atomicAdd(&h[b], 1);
            r->pairs[pos] = ((unsigned)(d & (BUCKET - 1)) << 17) | (unsigned)r->src[e];
        }
    }
}

// ---------------- per-bucket counting sort (device body) ----------------
// bin = ((d&7)<<7) | ((d>>3)<<4) | ch; run (16 bins) = (wave w=d&7, row r=d>>3).
static __device__ void sortb_body(const Rels& R, int bid) {
    const Rel* r;
    if (bid < R.r[1].oblk0) r = &R.r[0];
    else if (bid < R.r[2].oblk0) r = &R.r[1];
    else r = &R.r[2];
    int b = bid - r->oblk0;
    __shared__ int cnt[1024];
    __shared__ int sc[256];
    int t = threadIdx.x;
    for (int i = t; i < 1024; i += 256) cnt[i] = 0;
    __syncthreads();
    int j0 = r->boff[b], j1 = r->boff[b + 1];
    for (int j = j0 + t; j < j1; j += 256) {
        unsigned p = r->pairs[j];
        int d = (p >> 17) & 63;
        int ch = (int)((p & 0x1ffffu) >> CHSH); if (ch > 15) ch = 15;
        int bin = ((d & 7) << 7) | ((d >> 3) << 4) | ch;
        atomicAdd(&cnt[bin], 1);
    }
    __syncthreads();
    if (t < 64) {
        int b0 = ((t & 7) << 7) | ((t >> 3) << 4);
        int c = 0;
#pragma unroll
        for (int i = 0; i < 16; i++) c += cnt[b0 + i];
        int dd = (b << BSH) + t;
        if (dd < r->Ndst) r->invd[dd] = 1.f / (float)(c > 0 ? c : 1);
    }
    int c0 = cnt[4 * t], c1 = cnt[4 * t + 1], c2 = cnt[4 * t + 2], c3 = cnt[4 * t + 3];
    int tot = c0 + c1 + c2 + c3;
    sc[t] = tot;
    __syncthreads();
    for (int o = 1; o < 256; o <<= 1) {
        int x = (t >= o) ? sc[t - o] : 0;
        __syncthreads();
        sc[t] += x;
        __syncthreads();
    }
    int base = j0 + sc[t] - tot;
    if ((t & 3) == 0) r->goff[b * 64 + (t >> 2)] = base;
    cnt[4 * t] = base;
    cnt[4 * t + 1] = base + c0;
    cnt[4 * t + 2] = base + c0 + c1;
    cnt[4 * t + 3] = base + c0 + c1 + c2;
    if (t == 0 && b == r->nb - 1) r->goff[r->nb * 64] = r->E;
    __syncthreads();
    for (int j = j0 + t; j < j1; j += 256) {
        unsigned p = r->pairs[j];
        int d = (p >> 17) & 63;
        int ch = (int)((p & 0x1ffffu) >> CHSH); if (ch > 15) ch = 15;
        int bin = ((d & 7) << 7) | ((d >> 3) << 4) | ch;
        int pos = atomicAdd(&cnt[bin], 1);
        r->ssrc[pos] = p & 0x1ffffu;
    }
}

// ---------------- layer-1 MFMA GEMM body ----------------
// kw blocks: Zkw = x_kw@W0+bc1 (bf16), Yb = x_kw@W2 (bf16)
// rt blocks: Zrt, Ya, Yc (bf16), shared A read. A is f32 (converted in-reg).

struct GemmJobs {
    const float* Akw; int Nkw;
    const unsigned short* Wk1; const float* bk; unsigned short* Zkw;
    const unsigned short* Wk2; unsigned short* Ckw;
    const float* Art; int Nrt;
    const unsigned short* Wr1; const float* br; unsigned short* Zrt;
    const unsigned short* Wr2; unsigned short* Crt2;
    const unsigned short* Wr3; unsigned short* Crt3;
    int kwBlocks;
};

static __device__ void gemm_body(const GemmJobs& G, int bid) {
    bool iskw = bid < G.kwBlocks;
    const float* A = iskw ? G.Akw : G.Art;
    int N = iskw ? G.Nkw : G.Nrt;
    int lane = threadIdx.x & 63;
    int r16 = lane & 15, g = lane >> 4;
    int row0 = (iskw ? bid : bid - G.kwBlocks) * 64 + (threadIdx.x >> 6) * 16;
    int arow = row0 + r16;
    int arow_c = arow < N ? arow : N - 1;

    bf16x8 af[4];
    {
        const float* Af = A + (size_t)arow_c * 128 + g * 8;
#pragma unroll
        for (int kc = 0; kc < 4; kc++) {
            float4 u0 = *(const float4*)(Af + kc * 32);
            float4 u1 = *(const float4*)(Af + kc * 32 + 4);
            bf16x8 rr;
            rr[0] = (short)f2bf(u0.x); rr[1] = (short)f2bf(u0.y);
            rr[2] = (short)f2bf(u0.z); rr[3] = (short)f2bf(u0.w);
            rr[4] = (short)f2bf(u1.x); rr[5] = (short)f2bf(u1.y);
            rr[6] = (short)f2bf(u1.z); rr[7] = (short)f2bf(u1.w);
            af[kc] = rr;
        }
    }

    if (iskw) {
        f32x4 acc1[8], acc2[8];
#pragma unroll
        for (int ct = 0; ct < 8; ct++) { f32x4 z = {0.f,0.f,0.f,0.f}; acc1[ct] = z; acc2[ct] = z; }
#pragma unroll
        for (int kc = 0; kc < 4; kc++) {
#pragma unroll
            for (int ct = 0; ct < 8; ct++) {
                int wo = ((ct * 16 + r16) << 7) + kc * 32 + g * 8;
                bf16x8 b1 = *(const bf16x8*)(G.Wk1 + wo);
                acc1[ct] = __builtin_amdgcn_mfma_f32_16x16x32_bf16(af[kc], b1, acc1[ct], 0, 0, 0);
                bf16x8 b2 = *(const bf16x8*)(G.Wk2 + wo);
                acc2[ct] = __builtin_amdgcn_mfma_f32_16x16x32_bf16(af[kc], b2, acc2[ct], 0, 0, 0);
            }
        }
#pragma unroll
        for (int ct = 0; ct < 8; ct++) {
            int col = ct * 16 + r16;
            float bb = G.bk[col];
#pragma unroll
            for (int j = 0; j < 4; j++) {
                int r = row0 + g * 4 + j;
                if (r < N) {
                    G.Zkw[(size_t)r * 128 + col] = f2bf(acc1[ct][j] + bb);
                    G.Ckw[(size_t)r * 128 + col] = f2bf(acc2[ct][j]);
                }
            }
        }
    } else {
        f32x4 acc1[8], acc2[8], acc3[8];
#pragma unroll
        for (int ct = 0; ct < 8; ct++) {
            f32x4 z = {0.f,0.f,0.f,0.f}; acc1[ct] = z; acc2[ct] = z; acc3[ct] = z;
        }
#pragma unroll
        for (int kc = 0; kc < 4; kc++) {
#pragma unroll
            for (int ct = 0; ct < 8; ct++) {
                int wo = ((ct * 16 + r16) << 7) + kc * 32 + g * 8;
                bf16x8 b1 = *(const bf16x8*)(G.Wr1 + wo);
                acc1[ct] = __builtin_amdgcn_mfma_f32_16x16x32_bf16(af[kc], b1, acc1[ct], 0, 0, 0);
                bf16x8 b2 = *(const bf16x8*)(G.Wr2 + wo);
                acc2[ct] = __builtin_amdgcn_mfma_f32_16x16x32_bf16(af[kc], b2, acc2[ct], 0, 0, 0);
                bf16x8 b3 = *(const bf16x8*)(G.Wr3 + wo);
                acc3[ct] = __builtin_amdgcn_mfma_f32_16x16x32_bf16(af[kc], b3, acc3[ct], 0, 0, 0);
            }
        }
#pragma unroll
        for (int ct = 0; ct < 8; ct++) {
            int col = ct * 16 + r16;
            float bb = G.br[col];
#pragma unroll
            for (int j = 0; j < 4; j++) {
                int r = row0 + g * 4 + j;
                if (r < N) {
                    G.Zrt[(size_t)r * 128 + col] = f2bf(acc1[ct][j] + bb);
                    G.Crt2[(size_t)r * 128 + col] = f2bf(acc2[ct][j]);
                    G.Crt3[(size_t)r * 128 + col] = f2bf(acc3[ct][j]);
                }
            }
        }
    }
}

// gemm blocks + sort blocks merged (independent work, one launch)
__global__ __launch_bounds__(256) void gemm_sort_k(GemmJobs G, Rels R, int gemmBlocks) {
    if ((int)blockIdx.x < gemmBlocks) gemm_body(G, blockIdx.x);
    else sortb_body(R, blockIdx.x - gemmBlocks);
}

// ---------------- bucket aggregation (R7 structure) + optional fused L2 GEMM ----------------
// Block = one 64-dst bucket, 8 waves, LDS acc (stride 130). Wave w owns rows
// d=(r<<3)|w. Halves (h) process interleaved edges, 16 in flight, uint2 loads,
// packed f32x2 accumulate, shfl_xor(32) combine, non-atomic swizzled flush.
// GEPI=1: after relu-in-LDS, each wave runs the layer-2 GEMM for its 16-row
// A-tile straight from LDS (conflict-free b64 reads via the 130-stride pad).

struct AggJob {
    const unsigned short* Zin; int Ndst;
    const unsigned* sp0; const int* goff0; const float* invd0; const unsigned short* Y0;
    const unsigned* sp1; const int* goff1; const float* invd1; const unsigned short* Y1;
    int nrel;
    float* OutF; unsigned short* OutB;
    // fused layer-2 GEMM (GEPI=1): group0 waves -> Wg1(+bg1)->Cg1; group1 -> Wg2->Cg2 [,Wg3->Cg3]
    const unsigned short* Wg1; const float* bg1; unsigned short* Cg1;
    const unsigned short* Wg2; unsigned short* Cg2;
    const unsigned short* Wg3; unsigned short* Cg3;
};

template <int RELU, int OUTBF16, int GEPI>
__global__ __launch_bounds__(512, 8) void bagg2_k(AggJob JK, AggJob JR, int kwBlocks) {
    __shared__ float acc[BUCKET * ASTRIDE];
    bool iskw = blockIdx.x < (unsigned)kwBlocks;
    AggJob J = iskw ? JK : JR;
    int b = iskw ? blockIdx.x : blockIdx.x - kwBlocks;
    int t = threadIdx.x;
    int dst0 = b << BSH;
    int nrow = J.Ndst - dst0; if (nrow > BUCKET) nrow = BUCKET;

    // init from Zin bf16 (swizzled: feature 4m+e at r*ASTRIDE + e*32 + m); zero pad rows
    for (int c = t; c < BUCKET * 32; c += 512) {
        int r = c >> 5, m = c & 31;
        float z0 = 0.f, z1 = 0.f, z2 = 0.f, z3 = 0.f;
        if (r < nrow) {
            ushort4 z = *(const ushort4*)(J.Zin + (size_t)(dst0 + r) * 128 + (m << 2));
            z0 = bf2f(z.x); z1 = bf2f(z.y); z2 = bf2f(z.z); z3 = bf2f(z.w);
        }
        acc[r * ASTRIDE + m] = z0;
        acc[r * ASTRIDE + 32 + m] = z1;
        acc[r * ASTRIDE + 64 + m] = z2;
        acc[r * ASTRIDE + 96 + m] = z3;
    }
    __syncthreads();

    int w = t >> 6, lane = t & 63;
    int h = lane >> 5, q = lane & 31;
#pragma unroll 1
    for (int rel = 0; rel < J.nrel; rel++) {
        const unsigned* sp = rel ? J.sp1 : J.sp0;
        const int* goff = rel ? J.goff1 : J.goff0;
        const float* invd = rel ? J.invd1 : J.invd0;
        const unsigned short* Y = rel ? J.Y1 : J.Y0;
#pragma unroll 1
        for (int r = 0; r < 8; r++) {
            int g = b * 64 + w * 8 + r;
            int jg0 = goff[g], jg1 = goff[g + 1];
            if (jg0 >= jg1) continue;
            int d = (r << 3) | w;
            f32x2 a01 = {0.f, 0.f}, a23 = {0.f, 0.f};
#pragma unroll 1
            for (int j = jg0; j < jg1; j += 16) {
                uint2 v[8];
#pragma unroll
                for (int k = 0; k < 8; k++) {
                    int e = j + 2 * k + h;
                    e = e < jg1 ? e : jg1 - 1;
                    int s = (int)sp[e];
                    v[k] = *(const uint2*)(Y + ((size_t)s << 7) + (q << 2));
                }
#pragma unroll
                for (int k = 0; k < 8; k++) {
                    bool ok = (j + 2 * k + h) < jg1;
                    unsigned vx = ok ? v[k].x : 0u;
                    unsigned vy = ok ? v[k].y : 0u;
                    f32x2 x01 = { __uint_as_float(vx << 16),
                                  __uint_as_float(vx & 0xffff0000u) };
                    f32x2 x23 = { __uint_as_float(vy << 16),
                                  __uint_as_float(vy & 0xffff0000u) };
                    a01 += x01;
                    a23 += x23;
                }
            }
            a01[0] += __shfl_xor(a01[0], 32); a01[1] += __shfl_xor(a01[1], 32);
            a23[0] += __shfl_xor(a23[0], 32); a23[1] += __shfl_xor(a23[1], 32);
            float inv = invd[dst0 + d];
            float v0 = (h ? a23[0] : a01[0]) * inv;
            float v1 = (h ? a23[1] : a01[1]) * inv;
            int ba = d * ASTRIDE + q + h * 64;
            acc[ba] += v0;
            acc[ba + 32] += v1;
        }
    }
    __syncthreads();

    if (GEPI) {
        // relu in place (f32); A-tile stays in LDS, no global write of layer-1 act
        for (int c = t; c < BUCKET * 32; c += 512) {
            int r = c >> 5, m = c & 31;
            int ba = r * ASTRIDE + m;
            acc[ba] = fmaxf(acc[ba], 0.f);
            acc[ba + 32] = fmaxf(acc[ba + 32], 0.f);
            acc[ba + 64] = fmaxf(acc[ba + 64], 0.f);
            acc[ba + 96] = fmaxf(acc[ba + 96], 0.f);
        }
        __syncthreads();
        int r16 = lane & 15, gg = lane >> 4;
        int rg = (w & 3) * 16;
        // A-frags for rows rg+r16: feature f slot = (f&3)*32 + (f>>2)
        bf16x8 af[4];
        int rbase = (rg + r16) * ASTRIDE;
#pragma unroll
        for (int kc = 0; kc < 4; kc++) {
            int m2 = 2 * (kc * 4 + gg);
            float2 p0 = *(const float2*)&acc[rbase + m2];
            float2 p1 = *(const float2*)&acc[rbase + 32 + m2];
            float2 p2 = *(const float2*)&acc[rbase + 64 + m2];
            float2 p3 = *(const float2*)&acc[rbase + 96 + m2];
            bf16x8 rr;
            rr[0] = (short)f2bf(p0.x); rr[1] = (short)f2bf(p1.x);
            rr[2] = (short)f2bf(p2.x); rr[3] = (short)f2bf(p3.x);
            rr[4] = (short)f2bf(p0.y); rr[5] = (short)f2bf(p1.y);
            rr[6] = (short)f2bf(p2.y); rr[7] = (short)f2bf(p3.y);
            af[kc] = rr;
        }
        const unsigned short* WtA; unsigned short* CA; const float* biasA;
        const unsigned short* WtB = nullptr; unsigned short* CB = nullptr;
        if ((w >> 2) == 0) { WtA = J.Wg1; CA = J.Cg1; biasA = J.bg1; }
        else {
            WtA = J.Wg2; CA = J.Cg2; biasA = nullptr;
            if (J.Wg3) { WtB = J.Wg3; CB = J.Cg3; }
        }
        auto run_mat = [&](const unsigned short* Wt_, unsigned short* C_, const float* bias) {
#pragma unroll 1
            for (int ct = 0; ct < 8; ct++) {
                f32x4 a4 = {0.f, 0.f, 0.f, 0.f};
#pragma unroll
                for (int kc = 0; kc < 4; kc++) {
                    bf16x8 bfrag = *(const bf16x8*)(Wt_ + ((ct * 16 + r16) << 7) + kc * 32 + gg * 8);
                    a4 = __builtin_amdgcn_mfma_f32_16x16x32_bf16(af[kc], bfrag, a4, 0, 0, 0);
                }
                int col = ct * 16 + r16;
                float bb = bias ? bias[col] : 0.f;
#pragma unroll
                for (int jj = 0; jj < 4; jj++) {
                    int rloc = rg + gg * 4 + jj;
                    if (rloc < nrow)
                        C_[(size_t)(dst0 + rloc) * 128 + col] = f2bf(a4[jj] + bb);
                }
            }
        };
        run_mat(WtA, CA, biasA);
        if (WtB) run_mat(WtB, CB, nullptr);
        return;
    }

    for (int c = t; c < BUCKET * 32; c += 512) {
        int r = c >> 5, m = c & 31;
        if (r < nrow) {
            float x0 = acc[r * ASTRIDE + m];
            float x1 = acc[r * ASTRIDE + 32 + m];
            float x2 = acc[r * ASTRIDE + 64 + m];
            float x3 = acc[r * ASTRIDE + 96 + m];
            if (RELU) {
                x0 = fmaxf(x0, 0.f); x1 = fmaxf(x1, 0.f);
                x2 = fmaxf(x2, 0.f); x3 = fmaxf(x3, 0.f);
            }
            size_t o = (size_t)(dst0 + r) * 128 + (m << 2);
            if (OUTBF16) {
                ushort4 ov;
                ov.x = f2bf(x0); ov.y = f2bf(x1); ov.z = f2bf(x2); ov.w = f2bf(x3);
                *(ushort4*)(J.OutB + o) = ov;
            } else {
                *(float4*)(J.OutF + o) = make_float4(x0, x1, x2, x3);
            }
        }
    }
}

// ---------------- launch ----------------

static inline size_t align256(size_t x) { return (x + 255) & ~size_t(255); }

extern "C" void kernel_launch(void* const* d_in, const int* in_sizes, int n_in,
                              void* d_out, int out_size, void* d_ws, size_t ws_size,
                              hipStream_t stream) {
    const float* x_kw = (const float*)d_in[0];
    const float* x_rt = (const float*)d_in[1];
    const int* src_a = (const int*)d_in[2];
    const int* dst_a = (const int*)d_in[3];
    const int* src_b = (const int*)d_in[4];
    const int* dst_b = (const int*)d_in[5];
    const int* src_c = (const int*)d_in[6];
    const int* dst_c = (const int*)d_in[7];
    const float *Wl1a = (const float*)d_in[8],  *bl1a = (const float*)d_in[9],  *Wr1a = (const float*)d_in[10];
    const float *Wl1b = (const float*)d_in[11], *bl1b = (const float*)d_in[12], *Wr1b = (const float*)d_in[13];
    const float *Wl1c = (const float*)d_in[14], *bl1c = (const float*)d_in[15], *Wr1c = (const float*)d_in[16];
    const float *Wl2a = (const float*)d_in[17], *bl2a = (const float*)d_in[18], *Wr2a = (const float*)d_in[19];
    const float *Wl2b = (const float*)d_in[20], *bl2b = (const float*)d_in[21], *Wr2b = (const float*)d_in[22];
    const float *Wl2c = (const float*)d_in[23], *bl2c = (const float*)d_in[24], *Wr2c = (const float*)d_in[25];

    const int NKW = in_sizes[0] / 128;
    const int NRT = in_sizes[1] / 128;
    const int EA = in_sizes[2], EB = in_sizes[4], EC = in_sizes[6];
    const int nb_kw = (NKW + BUCKET - 1) / BUCKET;
    const int nb_rt = (NRT + BUCKET - 1) / BUCKET;

    char* ws = (char*)d_ws;
    size_t off = 0;
    auto alloc = [&](size_t bytes) -> char* {
        off = align256(off);
        char* p = ws + off;
        off += bytes;
        return p;
    };
    unsigned short* Wt = (unsigned short*)alloc(10 * 16384 * 2);
    float* bc1 = (float*)alloc(128 * 4);
    float* bc2 = (float*)alloc(128 * 4);
    int* bcnt3 = (int*)alloc(3 * NBMAX * 4);
    int* bcur3 = (int*)alloc(3 * NBMAX * 4);
    int* boff_a = (int*)alloc((NBMAX + 1) * 4);
    int* boff_b = (int*)alloc((NBMAX + 1) * 4);
    int* boff_c = (int*)alloc((NBMAX + 1) * 4);
    int* goff_a = (int*)alloc(((size_t)nb_kw * 64 + 1) * 4);
    int* goff_b = (int*)alloc(((size_t)nb_kw * 64 + 1) * 4);
    int* goff_c = (int*)alloc(((size_t)nb_rt * 64 + 1) * 4);
    float* invd_a = (float*)alloc((size_t)NKW * 4);
    float* invd_b = (float*)alloc((size_t)NKW * 4);
    float* invd_c = (float*)alloc((size_t)NRT * 4);
    unsigned* pairs_a = (unsigned*)alloc((size_t)EA * 4);
    unsigned* pairs_b = (unsigned*)alloc((size_t)EB * 4);
    unsigned* pairs_c = (unsigned*)alloc((size_t)EC * 4);
    unsigned* sp_a = (unsigned*)alloc((size_t)EA * 4);
    unsigned* sp_b = (unsigned*)alloc((size_t)EB * 4);
    unsigned* sp_c = (unsigned*)alloc((size_t)EC * 4);
    unsigned short* Ya = (unsigned short*)alloc((size_t)NRT * 128 * 2);
    unsigned short* Yb = (unsigned short*)alloc((size_t)NKW * 128 * 2);
    unsigned short* Yc = (unsigned short*)alloc((size_t)NRT * 128 * 2);
    unsigned short* Zkw = (unsigned short*)alloc((size_t)NKW * 128 * 2);
    unsigned short* Zrt = (unsigned short*)alloc((size_t)NRT * 128 * 2);
    unsigned short* Yb2 = (unsigned short*)alloc((size_t)NKW * 128 * 2);
    (void)ws_size;
    // layer-2 Y buffers for rt (5.12 MB each) alias dead pairs arrays (6.4 MB, dead after sortb)
    unsigned short* Ya2 = (unsigned short*)pairs_a;
    unsigned short* Yc2 = (unsigned short*)pairs_b;

    float* out_kw = (float*)d_out;
    float* out_rt = out_kw + (size_t)NKW * 128;

    // ---- Rels ----
    Rels R;
    int hA = 128, hB = 128, hC = 64;
    int sA = (EA + 8191) / 8192, sB = (EB + 8191) / 8192, sC = (EC + 8191) / 8192;
    R.r[0] = {src_a, dst_a, EA, nb_kw, NKW, 0, hA, 0, sA, 0,
              bcnt3, boff_a, bcur3, pairs_a, sp_a, goff_a, invd_a};
    R.r[1] = {src_b, dst_b, EB, nb_kw, NKW, hA, hB, sA, sB, nb_kw,
              bcnt3 + NBMAX, boff_b, bcur3 + NBMAX, pairs_b, sp_b, goff_b, invd_b};
    R.r[2] = {src_c, dst_c, EC, nb_rt, NRT, hA + hB, hC, sA + sB, sC, 2 * nb_kw,
              bcnt3 + 2 * NBMAX, boff_c, bcur3 + 2 * NBMAX, pairs_c, sp_c, goff_c, invd_c};

    // ---- prep + hist (one launch) ----
    hipMemsetAsync(bcnt3, 0, 3 * NBMAX * 4, stream);
    PrepArgs pa;
    pa.W[0] = Wr1a; pa.Wa[0] = Wr1b;
    pa.W[1] = Wl1a; pa.Wa[1] = nullptr;
    pa.W[2] = Wl1b; pa.Wa[2] = nullptr;
    pa.W[3] = Wl1c; pa.Wa[3] = nullptr;
    pa.W[4] = Wr1c; pa.Wa[4] = nullptr;
    pa.W[5] = Wr2a; pa.Wa[5] = Wr2b;
    pa.W[6] = Wl2a; pa.Wa[6] = nullptr;
    pa.W[7] = Wl2b; pa.Wa[7] = nullptr;
    pa.W[8] = Wl2c; pa.Wa[8] = nullptr;
    pa.W[9] = Wr2c; pa.Wa[9] = nullptr;
    pa.b1a = bl1a; pa.b1b = bl1b; pa.b2a = bl2a; pa.b2b = bl2b;
    prep_hist_k<<<641 + hA + hB + hC, 256, 0, stream>>>(pa, Wt, bc1, bc2, R, 641);
    unsigned short* W0 = Wt + 0 * 16384;
    unsigned short* W1 = Wt + 1 * 16384;
    unsigned short* W2 = Wt + 2 * 16384;
    unsigned short* W3 = Wt + 3 * 16384;
    unsigned short* W4 = Wt + 4 * 16384;
    unsigned short* W5 = Wt + 5 * 16384;
    unsigned short* W6 = Wt + 6 * 16384;
    unsigned short* W7 = Wt + 7 * 16384;
    unsigned short* W8 = Wt + 8 * 16384;
    unsigned short* W9 = Wt + 9 * 16384;

    bscan3_k<<<3, 1024, 0, stream>>>(R);
    bscatter3_k<<<sA + sB + sC, 256, 0, stream>>>(R);

    const int kwB = (NKW + 63) / 64, rtB = (NRT + 63) / 64;
    const int nsort = 2 * nb_kw + nb_rt;

    // ---- layer 1 GEMMs + bucket sort in one launch (independent) ----
    GemmJobs G1;
    G1.Akw = x_kw; G1.Nkw = NKW; G1.Wk1 = W0; G1.bk = bc1; G1.Zkw = Zkw; G1.Wk2 = W2; G1.Ckw = Yb;
    G1.Art = x_rt; G1.Nrt = NRT; G1.Wr1 = W4; G1.br = bl1c; G1.Zrt = Zrt;
    G1.Wr2 = W1; G1.Crt2 = Ya; G1.Wr3 = W3; G1.Crt3 = Yc;
    G1.kwBlocks = kwB;
    gemm_sort_k<<<kwB + rtB + nsort, 256, 0, stream>>>(G1, R, kwB + rtB);

    // ---- layer-1 agg + fused layer-2 GEMM ----
    AggJob JK1 = {Zkw, NKW, sp_a, goff_a, invd_a, Ya, sp_b, goff_b, invd_b, Yb, 2,
                  nullptr, nullptr,
                  W5, bc2, Zkw,      // Zkw2 = relu(kw1)@ (Wr2a+Wr2b) + bc2 (in place, own rows)
                  W7, Yb2,           // Yb2  = relu(kw1)@ Wl2b
                  nullptr, nullptr};
    AggJob JR1 = {Zrt, NRT, sp_c, goff_c, invd_c, Yc, nullptr, nullptr, nullptr, nullptr, 1,
                  nullptr, nullptr,
                  W9, bl2c, Zrt,     // Zrt2 = relu(rt1)@ Wr2c + bl2c
                  W6, Ya2,           // Ya2  = relu(rt1)@ Wl2a
                  W8, Yc2};          // Yc2  = relu(rt1)@ Wl2c
    bagg2_k<1, 1, 1><<<nb_kw + nb_rt, 512, 0, stream>>>(JK1, JR1, nb_kw);

    // ---- layer-2 agg ----
    AggJob JK2 = {Zkw, NKW, sp_a, goff_a, invd_a, Ya2, sp_b, goff_b, invd_b, Yb2, 2,
                  out_kw, nullptr,
                  nullptr, nullptr, nullptr, nullptr, nullptr, nullptr, nullptr};
    AggJob JR2 = {Zrt, NRT, sp_c, goff_c, invd_c, Yc2, nullptr, nullptr, nullptr, nullptr, 1,
                  out_rt, nullptr,
                  nullptr, nullptr, nullptr, nullptr, nullptr, nullptr, nullptr};
    bagg2_k<0, 0, 0><<<nb_kw + nb_rt, 512, 0, stream>>>(JK2, JR2, nb_kw);
}